// Round 6
// baseline (406.743 us; speedup 1.0000x reference)
//
#include <hip/hip_runtime.h>

#define H 64
#define NOBJ 512
#define BATCH 128
#define PACK_BLOCKS ((BATCH * NOBJ * NOBJ) / 1024)   // 16384

typedef __attribute__((ext_vector_type(8))) short s16x8;
typedef __attribute__((ext_vector_type(4))) float f32x4;
typedef __attribute__((ext_vector_type(4))) unsigned short u16x4;
typedef __attribute__((ext_vector_type(8))) unsigned short u16x8;

__device__ __forceinline__ unsigned short f2bf(float f) {
    unsigned int u = __float_as_uint(f);
    u += 0x7FFFu + ((u >> 16) & 1u);          // round-to-nearest-even
    return (unsigned short)(u >> 16);
}
__device__ __forceinline__ float bf2f(unsigned short h) {
    return __uint_as_float((unsigned int)h << 16);
}

#define MFMA16(a, b, c) __builtin_amdgcn_mfma_f32_16x16x32_bf16(a, b, c, 0, 0, 0)

// ---------------- Kernel 1: fused prep = mask-pack + MFMA projections ----------
// flat grid: blocks [0, 16384) pack mask {0.0,1.0} -> bits (134 MB -> 4.2 MB);
// blocks [16384, 19456) do the q/k/v projections (z = (gid-16384)>>10).
// Fusion removes the inter-kernel drain; streams overlap at the boundary.
__global__ __launch_bounds__(256) void prep_kernel(
    const float* __restrict__ mask, unsigned int* __restrict__ bits,
    const float* __restrict__ q, const float* __restrict__ k, const float* __restrict__ v,
    const float* __restrict__ Wq, const float* __restrict__ bq,
    const float* __restrict__ Wk, const float* __restrict__ bk,
    const float* __restrict__ Wv, const float* __restrict__ bv,
    unsigned short* __restrict__ qh, unsigned short* __restrict__ ql,
    unsigned short* __restrict__ kh, unsigned short* __restrict__ kl,
    unsigned short* __restrict__ vt)
{
    __shared__ unsigned short vtile[64][72];   // proj: [h][n] tile; pack: nibble buf
    const int tid = threadIdx.x;

    if (blockIdx.x < PACK_BLOCKS) {
        // ---- mask pack: 1024 floats/block ----
        unsigned char* nib = (unsigned char*)&vtile[0][0];
        const size_t base = (size_t)blockIdx.x * 1024;
        const f32x4 f = __builtin_nontemporal_load((const f32x4*)(mask + base + (size_t)tid * 4));
        nib[tid] = (unsigned char)((unsigned)(f[0] != 0.0f)
                 | ((unsigned)(f[1] != 0.0f) << 1)
                 | ((unsigned)(f[2] != 0.0f) << 2)
                 | ((unsigned)(f[3] != 0.0f) << 3));
        __syncthreads();
        if (tid < 32) {
            unsigned int wv = 0;
            #pragma unroll
            for (int i = 0; i < 8; ++i)
                wv |= (unsigned int)nib[tid * 8 + i] << (4 * i);
            bits[base / 32 + tid] = wv;
        }
        return;
    }

    // ---- projections ----
    const int p   = blockIdx.x - PACK_BLOCKS;
    const int z   = p >> 10;              // 0..2 = {q,k,v}
    const int rem = p & 1023;
    const int b   = rem >> 3;
    const int n0  = (rem & 7) * 64;

    const float* x; const float* W; const float* bias;
    unsigned short* yh; unsigned short* yl;
    if (z == 0)      { x = q; W = Wq; bias = bq; yh = qh; yl = ql; }
    else if (z == 1) { x = k; W = Wk; bias = bk; yh = kh; yl = kl; }
    else             { x = v; W = Wv; bias = bv; yh = nullptr; yl = nullptr; }

    const int lane = tid & 63;
    const int wt   = tid >> 6;
    const int l15  = lane & 15;
    const int lg   = lane >> 4;

    // W fragments: lane = (row ht*16+l15, k = kc*32+lg*8+j), k contiguous
    s16x8 wfh[4][2], wfl[4][2];
    #pragma unroll
    for (int ht = 0; ht < 4; ++ht) {
        #pragma unroll
        for (int kc = 0; kc < 2; ++kc) {
            const float* wp = W + (ht * 16 + l15) * H + kc * 32 + lg * 8;
            float4 f0 = *(const float4*)wp;
            float4 f1 = *(const float4*)(wp + 4);
            float f[8] = {f0.x, f0.y, f0.z, f0.w, f1.x, f1.y, f1.z, f1.w};
            s16x8 hi8, lo8;
            #pragma unroll
            for (int j = 0; j < 8; ++j) {
                const unsigned short hb = f2bf(f[j]);
                hi8[j] = (short)hb;
                lo8[j] = (short)f2bf(f[j] - bf2f(hb));
            }
            wfh[ht][kc] = hi8; wfl[ht][kc] = lo8;
        }
    }

    // x fragments: n = n0+wt*16+l15, x is [N,B,H]
    const int n = n0 + wt * 16 + l15;
    const float* xr = x + ((size_t)n * BATCH + b) * H;
    s16x8 xfh[2], xfl[2];
    #pragma unroll
    for (int kc = 0; kc < 2; ++kc) {
        const float* xp = xr + kc * 32 + lg * 8;
        float4 f0 = *(const float4*)xp;
        float4 f1 = *(const float4*)(xp + 4);
        float f[8] = {f0.x, f0.y, f0.z, f0.w, f1.x, f1.y, f1.z, f1.w};
        s16x8 hi8, lo8;
        #pragma unroll
        for (int j = 0; j < 8; ++j) {
            const unsigned short hb = f2bf(f[j]);
            hi8[j] = (short)hb;
            lo8[j] = (short)f2bf(f[j] - bf2f(hb));
        }
        xfh[kc] = hi8; xfl[kc] = lo8;
    }

    if (z < 2) {
        // D[h][n]: lane holds h = ht*16+lg*4+r, n fixed -> coalesced u16x4 stores
        #pragma unroll
        for (int ht = 0; ht < 4; ++ht) {
            const float4 b4 = *(const float4*)(bias + ht * 16 + lg * 4);
            f32x4 acc = {b4.x, b4.y, b4.z, b4.w};
            acc = MFMA16(wfh[ht][0], xfh[0], acc);
            acc = MFMA16(wfh[ht][1], xfh[1], acc);
            acc = MFMA16(wfh[ht][0], xfl[0], acc);
            acc = MFMA16(wfh[ht][1], xfl[1], acc);
            acc = MFMA16(wfl[ht][0], xfh[0], acc);
            acc = MFMA16(wfl[ht][1], xfh[1], acc);
            u16x4 hv, lv;
            #pragma unroll
            for (int r = 0; r < 4; ++r) {
                const unsigned short hb = f2bf(acc[r]);
                hv[r] = hb;
                lv[r] = f2bf(acc[r] - bf2f(hb));
            }
            const size_t o = ((size_t)b * NOBJ + n) * H + ht * 16 + lg * 4;
            *(u16x4*)(yh + o) = hv;
            *(u16x4*)(yl + o) = lv;
        }
    } else {
        // D[n][h] -> LDS tile -> coalesced vt [B,H,N] stores
        #pragma unroll
        for (int ht = 0; ht < 4; ++ht) {
            const float bs = bias[ht * 16 + l15];
            f32x4 acc = {bs, bs, bs, bs};
            acc = MFMA16(xfh[0], wfh[ht][0], acc);
            acc = MFMA16(xfh[1], wfh[ht][1], acc);
            acc = MFMA16(xfl[0], wfh[ht][0], acc);
            acc = MFMA16(xfl[1], wfh[ht][1], acc);
            acc = MFMA16(xfh[0], wfl[ht][0], acc);
            acc = MFMA16(xfh[1], wfl[ht][1], acc);
            u16x4 hv;
            #pragma unroll
            for (int r = 0; r < 4; ++r) hv[r] = f2bf(acc[r]);
            *(u16x4*)&vtile[ht * 16 + l15][wt * 16 + lg * 4] = hv;
        }
        __syncthreads();
        const int h = tid >> 2, nc = (tid & 3) * 16;
        const u16x8 d0 = *(const u16x8*)&vtile[h][nc];
        const u16x8 d1 = *(const u16x8*)&vtile[h][nc + 8];
        unsigned short* dst = vt + ((size_t)b * H + h) * NOBJ + n0 + nc;
        *(u16x8*)dst = d0;
        *(u16x8*)(dst + 8) = d1;
    }
}

// ---------------- Kernel 2: MFMA attention, XCD-colocated + 3-deep k ring ----
// 1-D grid 4096. Swizzle: xcd = orig&7, s = orig>>3, b = xcd + 8*(s>>5), nt = s&31
// (bijective). All 32 n-tiles of one b run consecutively on ONE XCD -> its
// k/q/vt/bits slice (~360 KB; ~4 bs in flight = 1.4 MB) stays in that XCD's 4 MB
// L2 -> load latency ~200 cy instead of ~900 -> Little's law unblocks BW.
// A/out stores are nontemporal (never re-read) to keep L2 for the read set.
__global__ __launch_bounds__(256, 4) void attn_kernel(
    const unsigned short* __restrict__ qh, const unsigned short* __restrict__ ql,
    const unsigned short* __restrict__ kh, const unsigned short* __restrict__ kl,
    const unsigned short* __restrict__ vt, const unsigned int* __restrict__ bits,
    float* __restrict__ out, float* __restrict__ Aout)
{
    __shared__ unsigned short sch[16][520];  // e hi strip, stride 260 dwords
    __shared__ unsigned short scl[16][520];  // e lo strip
    __shared__ float rsum[4][16];
    __shared__ float inv[16];

    const int tid  = threadIdx.x;
    const int lane = tid & 63;
    const int w    = tid >> 6;
    const int l15  = lane & 15;
    const int lg   = lane >> 4;

    const int orig = blockIdx.x;
    const int xcd  = orig & 7;
    const int s    = orig >> 3;
    const int b    = xcd + 8 * (s >> 5);
    const int n0   = (s & 31) * 16;

    // q fragments (B-operand): col n = l15, k = h contiguous
    const size_t qoff = ((size_t)b * NOBJ + n0 + l15) * H + lg * 8;
    const s16x8 qfh0 = *(const s16x8*)(qh + qoff);
    const s16x8 qfh1 = *(const s16x8*)(qh + qoff + 32);
    const s16x8 qfl0 = *(const s16x8*)(ql + qoff);
    const s16x8 qfl1 = *(const s16x8*)(ql + qoff + 32);

    const unsigned short* khp = kh + ((size_t)b * NOBJ + w * 128 + l15) * H + lg * 8;
    const unsigned short* klp = kl + ((size_t)b * NOBJ + w * 128 + l15) * H + lg * 8;

    // one uint4 = this row's mask bits for cols [w*128, w*128+128)
    const uint4 mw = *(const uint4*)(bits + ((size_t)b * NOBJ + n0 + l15) * (NOBJ / 32) + w * 4);
    const unsigned mwa[4] = {mw.x, mw.y, mw.z, mw.w};

    f32x4 ev[8];                 // exp(score)*mask kept in regs for the fp32 A-write
    float rp = 0.0f;

    // 3-buffer k-fragment ring, prefetch distance 2
    s16x8 ka[3][4];
#define LOADK(buf, mi)                                              \
    do {                                                            \
        const int _o = (mi) * 16 * H;                               \
        ka[buf][0] = *(const s16x8*)(khp + _o);                     \
        ka[buf][1] = *(const s16x8*)(khp + _o + 32);                \
        ka[buf][2] = *(const s16x8*)(klp + _o);                     \
        ka[buf][3] = *(const s16x8*)(klp + _o + 32);                \
    } while (0)

    LOADK(0, 0);
    LOADK(1, 1);

    #pragma unroll
    for (int mt = 0; mt < 8; ++mt) {
        const int cur = mt % 3;
        if (mt < 6) LOADK((mt + 2) % 3, mt + 2);

        f32x4 acc = {0.0f, 0.0f, 0.0f, 0.0f};           // C[m][n] = sum_h k[m][h] q[n][h]
        acc = MFMA16(ka[cur][0], qfh0, acc);
        acc = MFMA16(ka[cur][1], qfh1, acc);
        acc = MFMA16(ka[cur][0], qfl0, acc);
        acc = MFMA16(ka[cur][1], qfl1, acc);
        acc = MFMA16(ka[cur][2], qfh0, acc);
        acc = MFMA16(ka[cur][3], qfh1, acc);

        // mask bits for this mt: word mt>>1, bits (mt&1)*16 + lg*4 + r
        const unsigned wsel = mwa[mt >> 1] >> (((mt & 1) << 4) + (lg << 2));
        f32x4 e;
        #pragma unroll
        for (int r = 0; r < 4; ++r) {
            const float ex = __expf(acc[r] * 0.125f);
            e[r] = ((wsel >> r) & 1u) ? ex : 0.0f;
        }
        ev[mt] = e;
        rp += (e[0] + e[1]) + (e[2] + e[3]);

        u16x4 hv, lv;
        #pragma unroll
        for (int r = 0; r < 4; ++r) {
            const unsigned short hb = f2bf(e[r]);
            hv[r] = hb;
            lv[r] = f2bf(e[r] - bf2f(hb));
        }
        const int mo = w * 128 + mt * 16 + lg * 4;
        *(u16x4*)&sch[l15][mo] = hv;
        *(u16x4*)&scl[l15][mo] = lv;
    }
#undef LOADK

    rp += __shfl_xor(rp, 16);
    rp += __shfl_xor(rp, 32);
    if (lane < 16) rsum[w][lane] = rp;
    __syncthreads();
    if (tid < 16) {
        const float sv = (rsum[0][tid] + rsum[1][tid]) + (rsum[2][tid] + rsum[3][tid]);
        inv[tid] = 1.0f / (sv == 0.0f ? 1.0f : sv);
    }
    __syncthreads();

    // A write: fp32 from registers, nontemporal f32x4 per lane
    {
        const float iv = inv[l15];
        float* Arow = Aout + ((size_t)b * NOBJ + n0 + l15) * NOBJ + w * 128 + lg * 4;
        #pragma unroll
        for (int mt = 0; mt < 8; ++mt) {
            f32x4 a4;
            a4[0] = ev[mt][0] * iv; a4[1] = ev[mt][1] * iv;
            a4[2] = ev[mt][2] * iv; a4[3] = ev[mt][3] * iv;
            __builtin_nontemporal_store(a4, (f32x4*)(Arow + mt * 16));
        }
    }

    // AV: out[n][h] = inv[n] * sum_m e[n][m] * v[m][h]
    const unsigned short* vtp = vt + ((size_t)b * H + w * 16 + l15) * NOBJ + lg * 8;
    f32x4 o0 = {0.0f, 0.0f, 0.0f, 0.0f}, o1 = {0.0f, 0.0f, 0.0f, 0.0f};
    #pragma unroll
    for (int ks = 0; ks < 16; ks += 2) {
        const int mk = ks * 32 + lg * 8;
        const s16x8 ah0 = *(const s16x8*)&sch[l15][mk];
        const s16x8 al0 = *(const s16x8*)&scl[l15][mk];
        const s16x8 vf0 = *(const s16x8*)(vtp + ks * 32);
        o0 = MFMA16(ah0, vf0, o0);
        o0 = MFMA16(al0, vf0, o0);
        const s16x8 ah1 = *(const s16x8*)&sch[l15][mk + 32];
        const s16x8 al1 = *(const s16x8*)&scl[l15][mk + 32];
        const s16x8 vf1 = *(const s16x8*)(vtp + ks * 32 + 32);
        o1 = MFMA16(ah1, vf1, o1);
        o1 = MFMA16(al1, vf1, o1);
    }

    #pragma unroll
    for (int r = 0; r < 4; ++r) {
        const int nn = lg * 4 + r;                       // C row = n, col = h = l15
        __builtin_nontemporal_store((o0[r] + o1[r]) * inv[nn],
            out + ((size_t)(n0 + nn) * BATCH + b) * H + w * 16 + l15);
    }
}

extern "C" void kernel_launch(void* const* d_in, const int* in_sizes, int n_in,
                              void* d_out, int out_size, void* d_ws, size_t ws_size,
                              hipStream_t stream)
{
    (void)in_sizes; (void)n_in; (void)out_size; (void)ws_size;
    const float* q    = (const float*)d_in[0];
    const float* k    = (const float*)d_in[1];
    const float* v    = (const float*)d_in[2];
    const float* mask = (const float*)d_in[3];
    const float* Wq   = (const float*)d_in[4];
    const float* bq   = (const float*)d_in[5];
    const float* Wk   = (const float*)d_in[6];
    const float* bk   = (const float*)d_in[7];
    const float* Wv   = (const float*)d_in[8];
    const float* bv   = (const float*)d_in[9];

    float* out  = (float*)d_out;                                  // [N,B,H]
    float* Aout = (float*)d_out + (size_t)NOBJ * BATCH * H;       // [B,N,N]

    // workspace: 5 bf16 arrays (42 MB) + bitmask (4.2 MB)
    const size_t S = (size_t)BATCH * NOBJ * H;
    unsigned short* qh = (unsigned short*)d_ws;
    unsigned short* ql = qh + S;
    unsigned short* kh = ql + S;
    unsigned short* kl = kh + S;
    unsigned short* vt = kl + S;
    unsigned int* bits = (unsigned int*)(vt + S);

    prep_kernel<<<dim3(PACK_BLOCKS + 3 * BATCH * (NOBJ / 64)), 256, 0, stream>>>(
        mask, bits, q, k, v, Wq, bq, Wk, bk, Wv, bv, qh, ql, kh, kl, vt);
    attn_kernel<<<dim3((NOBJ / 16) * BATCH), 256, 0, stream>>>(
        qh, ql, kh, kl, vt, bits, out, Aout);
}